// Round 5
// baseline (305.984 us; speedup 1.0000x reference)
//
#include <hip/hip_runtime.h>
#include <stdint.h>

// Problem constants: x (32,384,56,56) fp32, weight (384,384) fp32,
// bias (384,) fp32. K=7 horizontal cyclic shifts.
#define B_   32
#define C_   384
#define H_   56
#define W_   56
#define HW_  (H_*W_)        // 3136
#define NP_  (B_*H_*W_)     // 100352
#define NWORD 6             // 384 / 64 bits
#define TPB  512            // threads per block (pack & bgemm)
#define NIT  7              // px iterations per thread (it 6: tid<64 only)
#define OQ   24             // output channels per bgemm block
#define NOB  (C_/OQ)        // 16

typedef unsigned long long u64;
typedef unsigned u32;

// dx(c) = (c + 3) % 7 - 3  ->  c%7 = 0..6 : {0,1,2,3,-3,-2,-1}

// ---------------------------------------------------------------------------
// Compile-time tables (algebra verbatim from the known-passing round-0).
// ---------------------------------------------------------------------------
struct Masks {
    u64 inv[7][NWORD];
    int nvalid[7];
};
constexpr Masks make_masks() {
    Masks m{};
    int wv[7] = {0, 1, 2, 3, 53, 54, 55};
    for (int p = 0; p < 7; ++p) {
        int nv = 0;
        for (int c = 0; c < C_; ++c) {
            int dx = (c + 3) % 7 - 3;
            int wp = wv[p] + dx;
            if (wp >= 0 && wp < W_) nv++;
            else m.inv[p][c >> 6] |= 1ull << (c & 63);
        }
        m.nvalid[p] = nv;
    }
    return m;
}
__device__ constexpr Masks MK = make_masks();

// u32-half invalid masks, indexed [w][kh] where kh = 32-channel group 0..11.
struct InvW32 { u32 m[W_][12]; };
constexpr InvW32 make_invw32() {
    InvW32 t{};
    for (int w = 0; w < W_; ++w)
        for (int kh = 0; kh < 12; ++kh)
            for (int j = 0; j < 32; ++j) {
                int c = kh * 32 + j;
                int dx = (c + 3) % 7 - 3;
                int wp = w + dx;
                if (!(wp >= 0 && wp < W_)) t.m[w][kh] |= 1u << j;
            }
    return t;
}
__device__ constexpr InvW32 IVW32 = make_invw32();

// u64 invalid masks for the fallback kernel.
struct InvW { u64 m[W_][NWORD]; };
constexpr InvW make_invw() {
    InvW t{};
    for (int w = 0; w < W_; ++w)
        for (int c = 0; c < C_; ++c) {
            int dx = (c + 3) % 7 - 3;
            int wp = w + dx;
            if (!(wp >= 0 && wp < W_)) t.m[w][c >> 6] |= 1ull << (c & 63);
        }
    return t;
}
__device__ constexpr InvW IVW = make_invw();

// ---------------------------------------------------------------------------
// Prep (verbatim): pw = packed sign(weight); C2[o][pat] = Nvalid(pat) +
// 2*popc(wbits & inv(pat)) + bias[o].  out = C2 - 2*popc(xm ^ wbits).
// ---------------------------------------------------------------------------
__global__ __launch_bounds__(64) void prep_kernel(
        const float* __restrict__ weight, const float* __restrict__ bias,
        u64* __restrict__ pw, float* __restrict__ C2) {
    int o = blockIdx.x;
    int lane = threadIdx.x;
    u64 words[NWORD];
#pragma unroll
    for (int k = 0; k < NWORD; ++k) {
        float v = weight[o * C_ + k * 64 + lane];
        words[k] = __ballot(v < 0.0f);
    }
    if (lane < NWORD) pw[o * NWORD + lane] = words[lane];
    if (lane < 7) {
        int wb = 0;
#pragma unroll
        for (int k = 0; k < NWORD; ++k)
            wb += __popcll(words[k] & MK.inv[lane][k]);
        C2[o * 7 + lane] = (float)(MK.nvalid[lane] + 2 * wb) + bias[o];
    }
}

// ---------------------------------------------------------------------------
// Pack: block = (b, kh) where kh selects 32 channels. The j-loop visits each
// x-plane ONCE; the whole block reads that plane's 12.5 KB contiguously
// (512 lanes x 7 it x 4B) before advancing to the next plane -> long
// monotonic DRAM read runs. Each thread accumulates 7 px-words (u32 halves).
// pk halves: u32[2] per u64 word; lo (j 0..31) and hi blocks write disjoint
// dwords of the same u64 array that bgemm reads.
// ---------------------------------------------------------------------------
template <int KH>
__device__ __forceinline__ void pack_body(
        const float* __restrict__ x, u32* __restrict__ pkw, int b) {
    constexpr int dxt[7] = {0, 1, 2, 3, -3, -2, -1};
    const int tid = threadIdx.x;

    int w_[NIT], rb_[NIT];
    u32 bits[NIT];
#pragma unroll
    for (int it = 0; it < NIT; ++it) {
        int px = tid + it * TPB;
        if (px > HW_ - 1) px = HW_ - 1;      // it=6 lanes>=64: clamped (unused)
        int w = px % W_;
        w_[it] = w;
        rb_[it] = px - w;
        bits[it] = 0;
    }

    const float* xb = x + ((size_t)b * C_ + KH * 32) * HW_;
#pragma unroll
    for (int j = 0; j < 32; ++j) {
        const int dx = dxt[(KH * 32 + j) % 7];        // compile-time
        const float* pb = xb + (size_t)j * HW_;       // uniform plane base
#pragma unroll
        for (int it = 0; it < NIT; ++it) {
            int wp = w_[it] + dx;
            int wc = wp < 0 ? 0 : (wp > W_ - 1 ? W_ - 1 : wp);
            u32 u = __float_as_uint(
                __builtin_nontemporal_load(&pb[rb_[it] + wc]));
            bits[it] |= (u >> 31) << j;
        }
    }

    const size_t base = (size_t)(KH >> 1) * NP_ + (size_t)b * HW_;
#pragma unroll
    for (int it = 0; it < NIT; ++it) {
        if (it < 6 || tid < 64) {                     // wave-uniform guard
            int px = tid + it * TPB;
            u32 v = bits[it] & ~IVW32.m[w_[it]][KH];
            pkw[((base + px) << 1) + (KH & 1)] = v;
        }
    }
}

__global__ __launch_bounds__(TPB) void pack_kernel(
        const float* __restrict__ x, u32* __restrict__ pkw) {
    const int b  = blockIdx.x / 12;
    const int kh = blockIdx.x % 12;
    switch (kh) {
        case 0:  pack_body<0>(x, pkw, b);  break;
        case 1:  pack_body<1>(x, pkw, b);  break;
        case 2:  pack_body<2>(x, pkw, b);  break;
        case 3:  pack_body<3>(x, pkw, b);  break;
        case 4:  pack_body<4>(x, pkw, b);  break;
        case 5:  pack_body<5>(x, pkw, b);  break;
        case 6:  pack_body<6>(x, pkw, b);  break;
        case 7:  pack_body<7>(x, pkw, b);  break;
        case 8:  pack_body<8>(x, pkw, b);  break;
        case 9:  pack_body<9>(x, pkw, b);  break;
        case 10: pack_body<10>(x, pkw, b); break;
        default: pack_body<11>(x, pkw, b); break;
    }
}

// ---------------------------------------------------------------------------
// bGEMM: block = (b, 24-output-channel chunk), 512 threads. Threads hold xw
// for a group of 3 pixels (px, px+512, px+1024); per output plane the block
// writes a 6 KB contiguous run, sweeping the 24 planes then advancing the
// pixel group -> the block's store stream is a monotonic 301 KB region.
// pk reads are L2/L3-resident (4.8 MB working set); weights s_load uniform.
// ---------------------------------------------------------------------------
template <int M>
__device__ __forceinline__ void bgemm_group(
        const u64* __restrict__ pk, const u64* __restrict__ pw,
        const float* __restrict__ C2, float* __restrict__ outb,
        int obase, int b, int it0) {
    const int tid = threadIdx.x;
    const size_t bhw = (size_t)b * HW_;

    int px[M], pat[M];
    u64 xw[M][NWORD];
#pragma unroll
    for (int m = 0; m < M; ++m) {
        px[m] = tid + (it0 + m) * TPB;
        int w = px[m] % W_;
        pat[m] = (w < 3) ? w : ((w >= 53) ? w - 49 : 3);
#pragma unroll
        for (int k = 0; k < NWORD; ++k)
            xw[m][k] = pk[(size_t)k * NP_ + bhw + px[m]];
    }

#pragma unroll 4
    for (int oi = 0; oi < OQ; ++oi) {
        const int o = obase + oi;
        const u64* wr = pw + o * NWORD;               // uniform -> s_load
#pragma unroll
        for (int m = 0; m < M; ++m) {
            int U = 0;
#pragma unroll
            for (int k = 0; k < NWORD; ++k)
                U += __popcll(xw[m][k] ^ wr[k]);
            float v = C2[o * 7 + pat[m]] - 2.0f * (float)U;
            __builtin_nontemporal_store(v, &outb[(size_t)o * HW_ + px[m]]);
        }
    }
}

__global__ __launch_bounds__(TPB) void bgemm_kernel(
        const u64* __restrict__ pk, const u64* __restrict__ pw,
        const float* __restrict__ C2, float* __restrict__ out) {
    const int b     = blockIdx.x / NOB;
    const int obase = (blockIdx.x % NOB) * OQ;
    float* outb = out + (size_t)b * C_ * HW_;

    bgemm_group<3>(pk, pw, C2, outb, obase, b, 0);    // px 0..1535
    bgemm_group<3>(pk, pw, C2, outb, obase, b, 3);    // px 1536..3071
    if (threadIdx.x < 64)                             // wave-uniform
        bgemm_group<1>(pk, pw, C2, outb, obase, b, 6); // px 3072..3135
}

// ---------------------------------------------------------------------------
// Fallback (known passing) if workspace is too small for pk.
// ---------------------------------------------------------------------------
__global__ __launch_bounds__(256) void cyclefc_fb_kernel(
        const float* __restrict__ x,
        const u64* __restrict__ pw,
        const float* __restrict__ C2,
        float* __restrict__ out) {
    unsigned p = blockIdx.x * 256u + threadIdx.x;
    unsigned w = p % (unsigned)W_;
    unsigned bh = p / (unsigned)W_;
    unsigned h = bh % (unsigned)H_;
    unsigned b = bh / (unsigned)H_;
    const float* xb = x + (size_t)b * C_ * HW_ + h * W_;

    constexpr int dxt[7] = {0, 1, 2, 3, -3, -2, -1};
    u64 xw[NWORD];
#pragma unroll
    for (int k = 0; k < NWORD; ++k) {
        u64 bits = 0;
#pragma unroll
        for (int j = 0; j < 64; ++j) {
            int dx = dxt[(k * 64 + j) % 7];
            int wp = (int)w + dx;
            int wpc = wp < 0 ? 0 : (wp > W_ - 1 ? W_ - 1 : wp);
            unsigned u = __float_as_uint(xb[(size_t)(k * 64 + j) * HW_ + wpc]);
            bits |= (u64)(u >> 31) << j;
        }
        xw[k] = bits & ~IVW.m[w][k];
    }
    int pat = (w < 3u) ? (int)w : ((w >= 53u) ? (int)w - 49 : 3);
    float* op = out + (size_t)b * C_ * HW_ + h * W_ + w;
#pragma unroll 4
    for (int o = 0; o < C_; ++o) {
        const u64* wr = pw + o * NWORD;
        int U = 0;
#pragma unroll
        for (int k = 0; k < NWORD; ++k)
            U += __popcll(xw[k] ^ wr[k]);
        op[(size_t)o * HW_] = C2[o * 7 + pat] - 2.0f * (float)U;
    }
}

extern "C" void kernel_launch(void* const* d_in, const int* in_sizes, int n_in,
                              void* d_out, int out_size, void* d_ws, size_t ws_size,
                              hipStream_t stream) {
    const float* x      = (const float*)d_in[0];
    const float* weight = (const float*)d_in[1];
    const float* bias   = (const float*)d_in[2];
    float* out = (float*)d_out;

    // ws layout: pw (18432 B) | C2 (10752 B) | pad to 32768 | pk (4816896 B)
    u64* pw = (u64*)d_ws;
    float* C2 = (float*)((char*)d_ws + C_ * NWORD * sizeof(u64));
    u64* pk = (u64*)((char*)d_ws + 32768);
    const size_t need = 32768 + (size_t)NWORD * NP_ * sizeof(u64);

    prep_kernel<<<dim3(C_), dim3(64), 0, stream>>>(weight, bias, pw, C2);

    if (ws_size >= need) {
        pack_kernel<<<dim3(B_ * 12), dim3(TPB), 0, stream>>>(x, (u32*)pk);
        bgemm_kernel<<<dim3(B_ * NOB), dim3(TPB), 0, stream>>>(pk, pw, C2, out);
    } else {
        cyclefc_fb_kernel<<<dim3(NP_ / 256), dim3(256), 0, stream>>>(x, pw, C2, out);
    }
}

// Round 6
// 275.545 us; speedup vs baseline: 1.1105x; 1.1105x over previous
//
#include <hip/hip_runtime.h>
#include <stdint.h>

// Problem constants (fixed by reference setup_inputs): x (32,384,56,56) fp32,
// weight (384,384) fp32, bias (384,) fp32. K=7 horizontal cyclic shifts.
#define B_   32
#define C_   384
#define H_   56
#define W_   56
#define HW_  (H_*W_)        // 3136
#define NP_  (B_*H_*W_)     // 100352 pixels = 392 * 256
#define NWORD 6             // 384 / 64 bits
#define PIXBLK 392          // NP_ / 256

// dx(c) = (c + 3) % 7 - 3  ->  c%7 = 0..6 : {0,1,2,3,-3,-2,-1}

// ---------------------------------------------------------------------------
// Compile-time tables.
// inv[pat][k]: bit c of word k set <=> channel c is out-of-bounds for edge
// pattern pat (pat = w for w<3, 3 for interior, w-49 for w>=53).
// invw[w][k]: same, indexed directly by w (for the pack kernel).
// ---------------------------------------------------------------------------
struct Masks {
    unsigned long long inv[7][NWORD];
    int nvalid[7];
};
constexpr Masks make_masks() {
    Masks m{};
    int wv[7] = {0, 1, 2, 3, 53, 54, 55};
    for (int p = 0; p < 7; ++p) {
        int nv = 0;
        for (int c = 0; c < C_; ++c) {
            int dx = (c + 3) % 7 - 3;
            int wp = wv[p] + dx;
            if (wp >= 0 && wp < W_) nv++;
            else m.inv[p][c >> 6] |= 1ull << (c & 63);
        }
        m.nvalid[p] = nv;
    }
    return m;
}
__device__ constexpr Masks MK = make_masks();

struct InvW { unsigned long long m[W_][NWORD]; };
constexpr InvW make_invw() {
    InvW t{};
    for (int w = 0; w < W_; ++w)
        for (int c = 0; c < C_; ++c) {
            int dx = (c + 3) % 7 - 3;
            int wp = w + dx;
            if (!(wp >= 0 && wp < W_)) t.m[w][c >> 6] |= 1ull << (c & 63);
        }
    return t;
}
__device__ constexpr InvW IVW = make_invw();

// ---------------------------------------------------------------------------
// Prep: pack sign(weight) into 6 uint64 per output channel via __ballot, and
// build C2[o][pat] = Nvalid(pat) + 2*popcount(wbits & inv(pat)) + bias[o].
// out = C2[o][pat] - 2*popcount(xm ^ wbits)  with invalid x-bits forced to 0.
// ---------------------------------------------------------------------------
__global__ __launch_bounds__(64) void prep_kernel(
        const float* __restrict__ weight, const float* __restrict__ bias,
        unsigned long long* __restrict__ pw, float* __restrict__ C2) {
    int o = blockIdx.x;
    int lane = threadIdx.x;
    unsigned long long words[NWORD];
#pragma unroll
    for (int k = 0; k < NWORD; ++k) {
        float v = weight[o * C_ + k * 64 + lane];
        words[k] = __ballot(v < 0.0f);   // bit c set <=> sign(weight)==-1
    }
    if (lane < NWORD) pw[o * NWORD + lane] = words[lane];
    if (lane < 7) {
        int wb = 0;
#pragma unroll
        for (int k = 0; k < NWORD; ++k)
            wb += __popcll(words[k] & MK.inv[lane][k]);
        C2[o * 7 + lane] = (float)(MK.nvalid[lane] + 2 * wb) + bias[o];
    }
}

// ---------------------------------------------------------------------------
// Kernel A: pack shifted sign(x) bits.  One thread per (pixel, word-of-64-
// channels).  k is wave-uniform (blockIdx-derived); the per-channel shift
// pattern is template-folded so dx and the bit position are compile-time.
// pk layout: [word][pixel]  ->  both A's stores and B's loads are coalesced.
// ---------------------------------------------------------------------------
template <int K>
__device__ __forceinline__ unsigned long long pack_word(
        const float* __restrict__ xb, int w) {
    constexpr int dxt[7] = {0, 1, 2, 3, -3, -2, -1};
    unsigned long long bits = 0;
#pragma unroll
    for (int j = 0; j < 64; ++j) {
        int dx = dxt[(K * 64 + j) % 7];          // folds after unroll
        int wp = w + dx;
        int wpc = wp < 0 ? 0 : (wp > W_ - 1 ? W_ - 1 : wp);  // clamp (masked later)
        unsigned u = __float_as_uint(
            __builtin_nontemporal_load(&xb[(size_t)j * HW_ + wpc]));
        bits |= (unsigned long long)(u >> 31) << j;
    }
    return bits & ~IVW.m[w][K];                  // zero out-of-bounds channels
}

__global__ __launch_bounds__(256) void pack_kernel(
        const float* __restrict__ x, unsigned long long* __restrict__ pk) {
    int k = blockIdx.x / PIXBLK;                              // word, uniform
    unsigned p = (blockIdx.x % PIXBLK) * 256u + threadIdx.x;  // pixel
    unsigned b = p / (unsigned)HW_;
    unsigned r = p % (unsigned)HW_;
    unsigned h = r / (unsigned)W_;
    int w = (int)(r % (unsigned)W_);

    const float* xb = x + ((size_t)b * C_ + k * 64) * HW_ + h * W_;

    unsigned long long bits;
    switch (k) {
        case 0: bits = pack_word<0>(xb, w); break;
        case 1: bits = pack_word<1>(xb, w); break;
        case 2: bits = pack_word<2>(xb, w); break;
        case 3: bits = pack_word<3>(xb, w); break;
        case 4: bits = pack_word<4>(xb, w); break;
        default: bits = pack_word<5>(xb, w); break;
    }
    pk[(size_t)k * NP_ + p] = bits;
}

// ---------------------------------------------------------------------------
// Kernel B: binary GEMM.  One thread per (pixel, 48-output-channel chunk).
// Weights are wave-uniform -> scalar loads; pk reads are coalesced and served
// from L2/L3 (4.8 MB total, read 8x); out stores are nontemporal (write-once).
// ---------------------------------------------------------------------------
__global__ __launch_bounds__(256) void bgemm_kernel(
        const unsigned long long* __restrict__ pk,
        const unsigned long long* __restrict__ pw,
        const float* __restrict__ C2,
        float* __restrict__ out) {
    int oc = blockIdx.x / PIXBLK;                             // o-chunk 0..7
    unsigned p = (blockIdx.x % PIXBLK) * 256u + threadIdx.x;  // pixel
    unsigned b = p / (unsigned)HW_;
    unsigned w = p % (unsigned)W_;
    int pat = (w < 3u) ? (int)w : ((w >= 53u) ? (int)w - 49 : 3);

    unsigned long long xw[NWORD];
#pragma unroll
    for (int k = 0; k < NWORD; ++k)
        xw[k] = pk[(size_t)k * NP_ + p];

    float* op = out + p + (size_t)b * (C_ - 1) * HW_;  // == b*C*HW + h*W + w

    const int obase = oc * (C_ / 8);                   // 48 channels
#pragma unroll 4
    for (int oi = 0; oi < C_ / 8; ++oi) {
        int o = obase + oi;
        const unsigned long long* wr = pw + o * NWORD; // uniform -> s_load
        int U = 0;
#pragma unroll
        for (int k = 0; k < NWORD; ++k)
            U += __popcll(xw[k] ^ wr[k]);
        float v = C2[o * 7 + pat] - 2.0f * (float)U;
        __builtin_nontemporal_store(v, &op[(size_t)o * HW_]);
    }
}

// ---------------------------------------------------------------------------
// Fallback (round-1 kernel, known passing) if workspace is too small for the
// 4.8 MB packed intermediate.
// ---------------------------------------------------------------------------
__global__ __launch_bounds__(256) void cyclefc_fb_kernel(
        const float* __restrict__ x,
        const unsigned long long* __restrict__ pw,
        const float* __restrict__ C2,
        float* __restrict__ out) {
    unsigned p = blockIdx.x * 256u + threadIdx.x;
    unsigned w = p % (unsigned)W_;
    unsigned bh = p / (unsigned)W_;
    unsigned h = bh % (unsigned)H_;
    unsigned b = bh / (unsigned)H_;
    const float* xb = x + (size_t)b * C_ * HW_ + h * W_;

    constexpr int dxt[7] = {0, 1, 2, 3, -3, -2, -1};
    unsigned long long xw[NWORD];
#pragma unroll
    for (int k = 0; k < NWORD; ++k) {
        unsigned long long bits = 0;
#pragma unroll
        for (int j = 0; j < 64; ++j) {
            int dx = dxt[(k * 64 + j) % 7];
            int wp = (int)w + dx;
            int wpc = wp < 0 ? 0 : (wp > W_ - 1 ? W_ - 1 : wp);
            unsigned u = __float_as_uint(xb[(size_t)(k * 64 + j) * HW_ + wpc]);
            bits |= (unsigned long long)(u >> 31) << j;
        }
        xw[k] = bits & ~IVW.m[w][k];
    }
    int pat = (w < 3u) ? (int)w : ((w >= 53u) ? (int)w - 49 : 3);
    float* op = out + (size_t)b * C_ * HW_ + h * W_ + w;
#pragma unroll 4
    for (int o = 0; o < C_; ++o) {
        const unsigned long long* wr = pw + o * NWORD;
        int U = 0;
#pragma unroll
        for (int k = 0; k < NWORD; ++k)
            U += __popcll(xw[k] ^ wr[k]);
        op[(size_t)o * HW_] = C2[o * 7 + pat] - 2.0f * (float)U;
    }
}

extern "C" void kernel_launch(void* const* d_in, const int* in_sizes, int n_in,
                              void* d_out, int out_size, void* d_ws, size_t ws_size,
                              hipStream_t stream) {
    const float* x      = (const float*)d_in[0];
    const float* weight = (const float*)d_in[1];
    const float* bias   = (const float*)d_in[2];
    float* out = (float*)d_out;

    // ws layout: pw (18432 B) | C2 (10752 B) | pad to 32768 | pk (4816896 B)
    unsigned long long* pw = (unsigned long long*)d_ws;
    float* C2 = (float*)((char*)d_ws + C_ * NWORD * sizeof(unsigned long long));
    unsigned long long* pk = (unsigned long long*)((char*)d_ws + 32768);
    const size_t need = 32768 + (size_t)NWORD * NP_ * sizeof(unsigned long long);

    prep_kernel<<<dim3(C_), dim3(64), 0, stream>>>(weight, bias, pw, C2);

    if (ws_size >= need) {
        pack_kernel<<<dim3(PIXBLK * NWORD), dim3(256), 0, stream>>>(x, pk);
        bgemm_kernel<<<dim3(PIXBLK * 8), dim3(256), 0, stream>>>(pk, pw, C2, out);
    } else {
        cyclefc_fb_kernel<<<dim3(NP_ / 256), dim3(256), 0, stream>>>(x, pw, C2, out);
    }
}